// Round 1
// baseline (637.589 us; speedup 1.0000x reference)
//
#include <hip/hip_runtime.h>
#include <hip/hip_bf16.h>

// LightGCL / LightGCN propagation:
//   x = concat(user_emb, item_emb)            [N=150000, d=64] fp32
//   acc = x; 3x { x = spmm(A, x); acc += x }  A: COO, E=1.2M
//   out = acc / 4
//
// Strategy: build CSR (sorted-by-row) once per call via histogram + scan +
// scatter (int atomics only), then 3 gather-based SpMM layers with no fp32
// atomics. One 64-lane wave per row, lane = dim -> each edge is one
// coalesced 256B read of x[col]. Accumulate out += 0.25*x inline.

#define EMB 64

__global__ void hist_kernel(const int* __restrict__ row, int* __restrict__ counts, int E) {
    int e = blockIdx.x * blockDim.x + threadIdx.x;
    if (e < E) atomicAdd(&counts[row[e] + 1], 1);
}

// inclusive scan of `in` (n elems) into `out`, 1024 elems/block, blockSums[b]=block total
__global__ void scan_blocks(const int* __restrict__ in, int* __restrict__ out,
                            int* __restrict__ blockSums, int n) {
    __shared__ int waveSums[4];
    int base = blockIdx.x * 1024 + threadIdx.x * 4;
    int v0 = (base + 0 < n) ? in[base + 0] : 0;
    int v1 = (base + 1 < n) ? in[base + 1] : 0;
    int v2 = (base + 2 < n) ? in[base + 2] : 0;
    int v3 = (base + 3 < n) ? in[base + 3] : 0;
    v1 += v0; v2 += v1; v3 += v2;
    int tsum = v3;
    int lane = threadIdx.x & 63;
    int wave = threadIdx.x >> 6;
    int s = tsum;
    #pragma unroll
    for (int off = 1; off < 64; off <<= 1) {
        int t = __shfl_up(s, off, 64);
        if (lane >= off) s += t;
    }
    if (lane == 63) waveSums[wave] = s;
    __syncthreads();
    int waveOff = 0;
    for (int w = 0; w < wave; w++) waveOff += waveSums[w];
    int thrExcl = waveOff + s - tsum;  // exclusive prefix for this thread
    if (base + 0 < n) out[base + 0] = v0 + thrExcl;
    if (base + 1 < n) out[base + 1] = v1 + thrExcl;
    if (base + 2 < n) out[base + 2] = v2 + thrExcl;
    if (base + 3 < n) out[base + 3] = v3 + thrExcl;
    if (threadIdx.x == 255) blockSums[blockIdx.x] = waveOff + s;
}

__global__ void scan_sums(int* blockSums, int nb) {
    if (blockIdx.x == 0 && threadIdx.x == 0) {
        int run = 0;
        for (int i = 0; i < nb; i++) { int v = blockSums[i]; blockSums[i] = run; run += v; }
    }
}

// row_ptr[i] += blockSumsExcl[i>>10]; cursor[i] = row_ptr[i] for i < nrows
__global__ void scan_add(int* __restrict__ rp, const int* __restrict__ bs,
                         int* __restrict__ cursor, int n, int nrows) {
    int idx = blockIdx.x * blockDim.x + threadIdx.x;
    if (idx < n) {
        int v = rp[idx] + bs[idx >> 10];
        rp[idx] = v;
        if (idx < nrows) cursor[idx] = v;
    }
}

__global__ void scatter_kernel(const int* __restrict__ row, const int* __restrict__ col,
                               const float* __restrict__ w, int* __restrict__ cursor,
                               int* __restrict__ col_s, float* __restrict__ w_s, int E) {
    int e = blockIdx.x * blockDim.x + threadIdx.x;
    if (e < E) {
        int p = atomicAdd(&cursor[row[e]], 1);
        col_s[p] = col[e];
        w_s[p] = w[e];
    }
}

// X0 = concat(user, item); out = 0.25 * X0
__global__ void init_kernel(const float* __restrict__ ue, const float* __restrict__ ie,
                            float* __restrict__ X0, float* __restrict__ out,
                            int nu_elems, int total) {
    int i = blockIdx.x * blockDim.x + threadIdx.x;
    if (i < total) {
        float v = (i < nu_elems) ? ue[i] : ie[i - nu_elems];
        X0[i] = v;
        out[i] = 0.25f * v;
    }
}

// one wave per row; lane = dim. Xout[row] = sum_e w*Xin[col]; out += 0.25*Xout
__global__ void spmm_kernel(const int* __restrict__ rp, const int* __restrict__ col_s,
                            const float* __restrict__ w_s, const float* __restrict__ Xin,
                            float* __restrict__ Xout, float* __restrict__ out, int nrows) {
    int gid = blockIdx.x * blockDim.x + threadIdx.x;
    int row = gid >> 6;
    int lane = gid & 63;
    if (row >= nrows) return;
    int beg = rp[row];
    int end = rp[row + 1];
    float acc = 0.0f;
    for (int e = beg; e < end; e++) {
        int c = col_s[e];
        float w = w_s[e];
        acc += w * Xin[(c << 6) + lane];
    }
    int o = (row << 6) + lane;
    Xout[o] = acc;
    out[o] += 0.25f * acc;
}

extern "C" void kernel_launch(void* const* d_in, const int* in_sizes, int n_in,
                              void* d_out, int out_size, void* d_ws, size_t ws_size,
                              hipStream_t stream) {
    const int* edge_row = (const int*)d_in[0];
    const int* edge_col = (const int*)d_in[1];
    const float* edge_w = (const float*)d_in[2];
    const float* user_emb = (const float*)d_in[3];
    const float* item_emb = (const float*)d_in[4];

    const int E = in_sizes[0];
    const int nu_elems = in_sizes[3];          // N_USERS * 64
    const int ni_elems = in_sizes[4];          // N_ITEMS * 64
    const int total = nu_elems + ni_elems;     // N * 64
    const int N = total / EMB;                 // 150000

    // workspace carve-out (256B aligned)
    size_t off = 0;
    auto carve = [&](size_t bytes) {
        void* p = (char*)d_ws + off;
        off += (bytes + 255) & ~(size_t)255;
        return p;
    };
    float* X0      = (float*)carve((size_t)total * 4);
    float* X1      = (float*)carve((size_t)total * 4);
    int*   counts  = (int*)carve((size_t)(N + 1) * 4);   // becomes row_ptr after scan
    int*   row_ptr = (int*)carve((size_t)(N + 1) * 4);
    int*   cursor  = (int*)carve((size_t)N * 4);
    int*   col_s   = (int*)carve((size_t)E * 4);
    float* w_s     = (float*)carve((size_t)E * 4);
    int*   bsums   = (int*)carve(4096);
    (void)ws_size;

    float* out = (float*)d_out;

    const int B = 256;
    const int nScan = N + 1;
    const int nb = (nScan + 1023) / 1024;

    hipMemsetAsync(counts, 0, (size_t)(N + 1) * 4, stream);

    hist_kernel<<<(E + B - 1) / B, B, 0, stream>>>(edge_row, counts, E);
    scan_blocks<<<nb, B, 0, stream>>>(counts, row_ptr, bsums, nScan);
    scan_sums<<<1, 64, 0, stream>>>(bsums, nb);
    scan_add<<<(nScan + B - 1) / B, B, 0, stream>>>(row_ptr, bsums, cursor, nScan, N);
    scatter_kernel<<<(E + B - 1) / B, B, 0, stream>>>(edge_row, edge_col, edge_w,
                                                      cursor, col_s, w_s, E);
    init_kernel<<<(total + B - 1) / B, B, 0, stream>>>(user_emb, item_emb, X0, out,
                                                       nu_elems, total);

    float* Xin = X0;
    float* Xout = X1;
    for (int layer = 0; layer < 3; layer++) {
        spmm_kernel<<<(total + B - 1) / B, B, 0, stream>>>(row_ptr, col_s, w_s,
                                                           Xin, Xout, out, N);
        float* t = Xin; Xin = Xout; Xout = t;
    }
}

// Round 2
// 426.774 us; speedup vs baseline: 1.4940x; 1.4940x over previous
//
#include <hip/hip_runtime.h>
#include <hip/hip_bf16.h>

// LightGCN propagation: x = concat(user,item) [150000,64] f32;
// acc = x; 3x { x = A@x (COO spmm, E=1.2M); acc += x }; out = acc/4.
//
// CSR built per call (histogram -> scan -> scatter, int atomics only).
// SpMM: one wave per row, wave split into 4x16-lane groups; each group
// processes one edge with float4 loads (256B/edge coalesced), 2x unrolled
// => 8 independent gathers in flight per wave (vs 1 in the naive loop).
// (col,w) packed as int2. Layer 1 gathers directly from user/item arrays
// and fuses the out = 0.25*(x0 + x1) init. Layer 3 skips the Xout store.

#define EMB 64

__global__ void hist_kernel(const int* __restrict__ row, int* __restrict__ counts, int E) {
    int e = blockIdx.x * blockDim.x + threadIdx.x;
    if (e < E) atomicAdd(&counts[row[e] + 1], 1);
}

// inclusive scan of `in` (n elems) into `out`, 1024 elems/block
__global__ void scan_blocks(const int* __restrict__ in, int* __restrict__ out,
                            int* __restrict__ blockSums, int n) {
    __shared__ int waveSums[4];
    int base = blockIdx.x * 1024 + threadIdx.x * 4;
    int v0 = (base + 0 < n) ? in[base + 0] : 0;
    int v1 = (base + 1 < n) ? in[base + 1] : 0;
    int v2 = (base + 2 < n) ? in[base + 2] : 0;
    int v3 = (base + 3 < n) ? in[base + 3] : 0;
    v1 += v0; v2 += v1; v3 += v2;
    int tsum = v3;
    int lane = threadIdx.x & 63;
    int wave = threadIdx.x >> 6;
    int s = tsum;
    #pragma unroll
    for (int off = 1; off < 64; off <<= 1) {
        int t = __shfl_up(s, off, 64);
        if (lane >= off) s += t;
    }
    if (lane == 63) waveSums[wave] = s;
    __syncthreads();
    int waveOff = 0;
    for (int w = 0; w < wave; w++) waveOff += waveSums[w];
    int thrExcl = waveOff + s - tsum;
    if (base + 0 < n) out[base + 0] = v0 + thrExcl;
    if (base + 1 < n) out[base + 1] = v1 + thrExcl;
    if (base + 2 < n) out[base + 2] = v2 + thrExcl;
    if (base + 3 < n) out[base + 3] = v3 + thrExcl;
    if (threadIdx.x == 255) blockSums[blockIdx.x] = waveOff + s;
}

__global__ void scan_sums(int* blockSums, int nb) {
    if (blockIdx.x == 0 && threadIdx.x == 0) {
        int run = 0;
        for (int i = 0; i < nb; i++) { int v = blockSums[i]; blockSums[i] = run; run += v; }
    }
}

__global__ void scan_add(int* __restrict__ rp, const int* __restrict__ bs,
                         int* __restrict__ cursor, int n, int nrows) {
    int idx = blockIdx.x * blockDim.x + threadIdx.x;
    if (idx < n) {
        int v = rp[idx] + bs[idx >> 10];
        rp[idx] = v;
        if (idx < nrows) cursor[idx] = v;
    }
}

__global__ void scatter_kernel(const int* __restrict__ row, const int* __restrict__ col,
                               const float* __restrict__ w, int* __restrict__ cursor,
                               int2* __restrict__ cw_s, int E) {
    int e = blockIdx.x * blockDim.x + threadIdx.x;
    if (e < E) {
        int p = atomicAdd(&cursor[row[e]], 1);
        cw_s[p] = make_int2(col[e], __float_as_int(w[e]));
    }
}

// One wave per row. 4 edge-groups of 16 lanes; float4/lane; 2x unroll.
// FIRST: gather from split user/item arrays; out = 0.25*(x0 + acc).
// !FIRST: gather from Xin; out += 0.25*acc.
// WRITE_X: store Xout (skipped on last layer).
template <bool FIRST, bool WRITE_X>
__global__ void spmm_kernel(const int* __restrict__ rp, const int2* __restrict__ cw,
                            const float* __restrict__ Xin,
                            const float* __restrict__ ue, const float* __restrict__ ie,
                            int nuRows,
                            float* __restrict__ Xout, float* __restrict__ out, int nrows) {
    int wid = (blockIdx.x * blockDim.x + threadIdx.x) >> 6;
    if (wid >= nrows) return;
    int lane = threadIdx.x & 63;
    int sub = lane >> 4;   // which edge in the group of 4
    int l16 = lane & 15;   // float4 slot within the row

    int beg = rp[wid];
    int end = rp[wid + 1];

    float ax = 0.f, ay = 0.f, az = 0.f, aw = 0.f;
    int e = beg + sub;
    for (; e + 4 < end; e += 8) {
        int2 c0 = cw[e];
        int2 c1 = cw[e + 4];
        const float4* p0;
        const float4* p1;
        if (FIRST) {
            p0 = (const float4*)(c0.x < nuRows ? ue + ((size_t)c0.x << 6)
                                               : ie + ((size_t)(c0.x - nuRows) << 6));
            p1 = (const float4*)(c1.x < nuRows ? ue + ((size_t)c1.x << 6)
                                               : ie + ((size_t)(c1.x - nuRows) << 6));
        } else {
            p0 = (const float4*)(Xin + ((size_t)c0.x << 6));
            p1 = (const float4*)(Xin + ((size_t)c1.x << 6));
        }
        float4 v0 = p0[l16];
        float4 v1 = p1[l16];
        float w0 = __int_as_float(c0.y);
        float w1 = __int_as_float(c1.y);
        ax += w0 * v0.x + w1 * v1.x;
        ay += w0 * v0.y + w1 * v1.y;
        az += w0 * v0.z + w1 * v1.z;
        aw += w0 * v0.w + w1 * v1.w;
    }
    if (e < end) {
        int2 c0 = cw[e];
        const float4* p0;
        if (FIRST) {
            p0 = (const float4*)(c0.x < nuRows ? ue + ((size_t)c0.x << 6)
                                               : ie + ((size_t)(c0.x - nuRows) << 6));
        } else {
            p0 = (const float4*)(Xin + ((size_t)c0.x << 6));
        }
        float4 v0 = p0[l16];
        float w0 = __int_as_float(c0.y);
        ax += w0 * v0.x;
        ay += w0 * v0.y;
        az += w0 * v0.z;
        aw += w0 * v0.w;
    }

    // reduce the 4 edge-groups (xor 16, then 32 -> every lane holds full sum)
    ax += __shfl_xor(ax, 16, 64); ax += __shfl_xor(ax, 32, 64);
    ay += __shfl_xor(ay, 16, 64); ay += __shfl_xor(ay, 32, 64);
    az += __shfl_xor(az, 16, 64); az += __shfl_xor(az, 32, 64);
    aw += __shfl_xor(aw, 16, 64); aw += __shfl_xor(aw, 32, 64);

    size_t ro = (size_t)wid << 6;
    if (WRITE_X && sub == 0) {
        float4 s = make_float4(ax, ay, az, aw);
        ((float4*)(Xout + ro))[l16] = s;
    }
    if (sub == 1) {
        float4* po = (float4*)(out + ro);
        if (FIRST) {
            const float4* px0 = (const float4*)(wid < nuRows ? ue + ((size_t)wid << 6)
                                                             : ie + ((size_t)(wid - nuRows) << 6));
            float4 x0 = px0[l16];
            float4 o;
            o.x = 0.25f * (x0.x + ax);
            o.y = 0.25f * (x0.y + ay);
            o.z = 0.25f * (x0.z + az);
            o.w = 0.25f * (x0.w + aw);
            po[l16] = o;
        } else {
            float4 o = po[l16];
            o.x += 0.25f * ax;
            o.y += 0.25f * ay;
            o.z += 0.25f * az;
            o.w += 0.25f * aw;
            po[l16] = o;
        }
    }
}

extern "C" void kernel_launch(void* const* d_in, const int* in_sizes, int n_in,
                              void* d_out, int out_size, void* d_ws, size_t ws_size,
                              hipStream_t stream) {
    const int* edge_row = (const int*)d_in[0];
    const int* edge_col = (const int*)d_in[1];
    const float* edge_w = (const float*)d_in[2];
    const float* user_emb = (const float*)d_in[3];
    const float* item_emb = (const float*)d_in[4];

    const int E = in_sizes[0];
    const int nu_elems = in_sizes[3];
    const int ni_elems = in_sizes[4];
    const int total = nu_elems + ni_elems;
    const int N = total / EMB;          // 150000
    const int nuRows = nu_elems / EMB;  // 100000

    size_t off = 0;
    auto carve = [&](size_t bytes) {
        void* p = (char*)d_ws + off;
        off += (bytes + 255) & ~(size_t)255;
        return p;
    };
    float* X1      = (float*)carve((size_t)total * 4);
    float* X2      = (float*)carve((size_t)total * 4);
    int*   counts  = (int*)carve((size_t)(N + 1) * 4);
    int*   row_ptr = (int*)carve((size_t)(N + 1) * 4);
    int*   cursor  = (int*)carve((size_t)N * 4);
    int2*  cw_s    = (int2*)carve((size_t)E * 8);
    int*   bsums   = (int*)carve(4096);
    (void)ws_size;

    float* out = (float*)d_out;

    const int B = 256;
    const int nScan = N + 1;
    const int nb = (nScan + 1023) / 1024;

    hipMemsetAsync(counts, 0, (size_t)(N + 1) * 4, stream);

    hist_kernel<<<(E + B - 1) / B, B, 0, stream>>>(edge_row, counts, E);
    scan_blocks<<<nb, B, 0, stream>>>(counts, row_ptr, bsums, nScan);
    scan_sums<<<1, 64, 0, stream>>>(bsums, nb);
    scan_add<<<(nScan + B - 1) / B, B, 0, stream>>>(row_ptr, bsums, cursor, nScan, N);
    scatter_kernel<<<(E + B - 1) / B, B, 0, stream>>>(edge_row, edge_col, edge_w,
                                                      cursor, cw_s, E);

    const int spmmBlocks = (N * 64 + B - 1) / B;  // one wave per row
    // layer 1: gather from user/item, write X1, out = 0.25*(x0+x1)
    spmm_kernel<true, true><<<spmmBlocks, B, 0, stream>>>(row_ptr, cw_s, nullptr,
                                                          user_emb, item_emb, nuRows,
                                                          X1, out, N);
    // layer 2: X1 -> X2, out += 0.25*x2
    spmm_kernel<false, true><<<spmmBlocks, B, 0, stream>>>(row_ptr, cw_s, X1,
                                                           nullptr, nullptr, nuRows,
                                                           X2, out, N);
    // layer 3: X2 -> (discard), out += 0.25*x3
    spmm_kernel<false, false><<<spmmBlocks, B, 0, stream>>>(row_ptr, cw_s, X2,
                                                            nullptr, nullptr, nuRows,
                                                            nullptr, out, N);
}

// Round 3
// 394.502 us; speedup vs baseline: 1.6162x; 1.0818x over previous
//
#include <hip/hip_runtime.h>
#include <hip/hip_bf16.h>

// LightGCN propagation: x = concat(user,item) [150000,64] f32;
// acc = x; 3x { x = A@x (COO spmm, E=1.2M); acc += x }; out = acc/4.
//
// Pipeline:
//  1) hist: per-row edge counts (global atomics, 600KB table).
//  2) scan -> row_ptr.
//  3) two-phase binned CSR build (bucket = row>>9, 293 buckets):
//     scatter1: LDS-rank edges per bucket within 4096-edge blocks, reserve
//       chunks with one global atomic per (block,bucket), write (r,c,w) to
//       bucket-contiguous tmp  -> write amplification ~1 (was 8x).
//     scatter2: one block per bucket; place at row_ptr[r] + LDS-rank; all
//       writes land in a ~32KB window, zero global atomics.
//  4) X staged in fp16 (halves gather traffic). SpMM: 1 wave/row, 8 edge-
//     groups x 8 lanes x 16B loads => 16 independent gathers in flight.
//  5) final: out = 0.25*(x0_fp32 + x1h + x2h + x3h)  (no RMW in spmm).

#define EMB 64
#define BUCKET_SHIFT 9                 // 512 rows per bucket
#define S1_CHUNK 4096                  // edges per scatter1 block
#define NBUCK_PAD 320

typedef _Float16 h8 __attribute__((ext_vector_type(8)));
typedef float f4 __attribute__((ext_vector_type(4)));

__global__ void hist_kernel(const int* __restrict__ row, int* __restrict__ counts, int E) {
    int e = blockIdx.x * blockDim.x + threadIdx.x;
    if (e < E) atomicAdd(&counts[row[e] + 1], 1);
}

// inclusive scan, 1024 elems/block
__global__ void scan_blocks(const int* __restrict__ in, int* __restrict__ out,
                            int* __restrict__ blockSums, int n) {
    __shared__ int waveSums[4];
    int base = blockIdx.x * 1024 + threadIdx.x * 4;
    int v0 = (base + 0 < n) ? in[base + 0] : 0;
    int v1 = (base + 1 < n) ? in[base + 1] : 0;
    int v2 = (base + 2 < n) ? in[base + 2] : 0;
    int v3 = (base + 3 < n) ? in[base + 3] : 0;
    v1 += v0; v2 += v1; v3 += v2;
    int tsum = v3;
    int lane = threadIdx.x & 63;
    int wave = threadIdx.x >> 6;
    int s = tsum;
    #pragma unroll
    for (int off = 1; off < 64; off <<= 1) {
        int t = __shfl_up(s, off, 64);
        if (lane >= off) s += t;
    }
    if (lane == 63) waveSums[wave] = s;
    __syncthreads();
    int waveOff = 0;
    for (int w = 0; w < wave; w++) waveOff += waveSums[w];
    int thrExcl = waveOff + s - tsum;
    if (base + 0 < n) out[base + 0] = v0 + thrExcl;
    if (base + 1 < n) out[base + 1] = v1 + thrExcl;
    if (base + 2 < n) out[base + 2] = v2 + thrExcl;
    if (base + 3 < n) out[base + 3] = v3 + thrExcl;
    if (threadIdx.x == 255) blockSums[blockIdx.x] = waveOff + s;
}

__global__ void scan_sums(int* blockSums, int nb) {
    if (blockIdx.x == 0 && threadIdx.x == 0) {
        int run = 0;
        for (int i = 0; i < nb; i++) { int v = blockSums[i]; blockSums[i] = run; run += v; }
    }
}

__global__ void scan_add(int* __restrict__ rp, const int* __restrict__ bs, int n) {
    int idx = blockIdx.x * blockDim.x + threadIdx.x;
    if (idx < n) rp[idx] += bs[idx >> 10];
}

__global__ void init_cursor1(const int* __restrict__ rp, int* __restrict__ cursor1,
                             int nbuck, int nrows) {
    int j = blockIdx.x * blockDim.x + threadIdx.x;
    if (j < nbuck) {
        int r = j << BUCKET_SHIFT;
        cursor1[j] = rp[r < nrows ? r : nrows];
    }
}

// x0 fp32 (split arrays) -> fp16, 8 elems/thread
__global__ void convert_kernel(const float* __restrict__ ue, const float* __restrict__ ie,
                               h8* __restrict__ X0h, int nu_elems, int total8) {
    int t = blockIdx.x * blockDim.x + threadIdx.x;
    if (t >= total8) return;
    int base = t << 3;
    const f4* src = (const f4*)((base < nu_elems) ? (ue + base) : (ie + (base - nu_elems)));
    f4 a = src[0], b = src[1];
    h8 o;
    o[0] = (_Float16)a.x; o[1] = (_Float16)a.y; o[2] = (_Float16)a.z; o[3] = (_Float16)a.w;
    o[4] = (_Float16)b.x; o[5] = (_Float16)b.y; o[6] = (_Float16)b.z; o[7] = (_Float16)b.w;
    X0h[t] = o;
}

// phase 1 of the binned sort: rank in LDS, reserve chunk, write tmp
__global__ void scatter1(const int* __restrict__ row, const int* __restrict__ col,
                         const float* __restrict__ w, int* __restrict__ cursor1,
                         int* __restrict__ tmp_r, int2* __restrict__ tmp_cw,
                         int nbuck, int E) {
    __shared__ int lcount[NBUCK_PAD];
    __shared__ int lbase[NBUCK_PAD];
    int t = threadIdx.x;
    int c0 = blockIdx.x * S1_CHUNK;
    for (int j = t; j < nbuck; j += 256) lcount[j] = 0;
    __syncthreads();
    int pk[16];
    #pragma unroll
    for (int i = 0; i < 16; i++) {
        int e = c0 + i * 256 + t;
        int p = -1;
        if (e < E) {
            int b = row[e] >> BUCKET_SHIFT;
            int r = atomicAdd(&lcount[b], 1);
            p = (b << 13) | r;
        }
        pk[i] = p;
    }
    __syncthreads();
    for (int j = t; j < nbuck; j += 256) {
        int c = lcount[j];
        if (c) lbase[j] = atomicAdd(&cursor1[j], c);
    }
    __syncthreads();
    #pragma unroll
    for (int i = 0; i < 16; i++) {
        int e = c0 + i * 256 + t;
        if (e < E) {
            int b = pk[i] >> 13;
            int r = pk[i] & 8191;
            int p = lbase[b] + r;
            tmp_r[p] = row[e];
            tmp_cw[p] = make_int2(col[e], __float_as_int(w[e]));
        }
    }
}

// phase 2: one block per bucket; place edges at row_ptr[r] + LDS rank
__global__ void scatter2(const int* __restrict__ rp, const int* __restrict__ tmp_r,
                         const int2* __restrict__ tmp_cw, int2* __restrict__ cw,
                         int nrows) {
    __shared__ int lcnt[1 << BUCKET_SHIFT];
    int j = blockIdx.x;
    for (int k = threadIdx.x; k < (1 << BUCKET_SHIFT); k += 256) lcnt[k] = 0;
    __syncthreads();
    int rowbase = j << BUCKET_SHIFT;
    int rend = rowbase + (1 << BUCKET_SHIFT);
    if (rend > nrows) rend = nrows;
    int beg = rp[rowbase];
    int end = rp[rend];
    for (int p = beg + threadIdx.x; p < end; p += 256) {
        int r = tmp_r[p];
        int rank = atomicAdd(&lcnt[r & ((1 << BUCKET_SHIFT) - 1)], 1);
        cw[rp[r] + rank] = tmp_cw[p];
    }
}

// 1 wave/row; 8 edge-groups x 8 lanes; each lane: 16B (8 fp16 dims); 2x unroll
__global__ void spmm_kernel(const int* __restrict__ rp, const int2* __restrict__ cw,
                            const h8* __restrict__ Xin, h8* __restrict__ Xout,
                            int nrows) {
    int wid = (blockIdx.x * blockDim.x + threadIdx.x) >> 6;
    if (wid >= nrows) return;
    int lane = threadIdx.x & 63;
    int sub = lane >> 3;   // edge slot 0..7
    int l8 = lane & 7;     // dim chunk (8 dims)

    int beg = rp[wid];
    int end = rp[wid + 1];

    float acc[8];
    #pragma unroll
    for (int k = 0; k < 8; k++) acc[k] = 0.f;

    int e = beg + sub;
    for (; e + 8 < end; e += 16) {
        int2 c0 = cw[e];
        int2 c1 = cw[e + 8];
        h8 v0 = Xin[(c0.x << 3) + l8];
        h8 v1 = Xin[(c1.x << 3) + l8];
        float w0 = __int_as_float(c0.y);
        float w1 = __int_as_float(c1.y);
        #pragma unroll
        for (int k = 0; k < 8; k++)
            acc[k] += w0 * (float)v0[k] + w1 * (float)v1[k];
    }
    if (e < end) {
        int2 c0 = cw[e];
        h8 v0 = Xin[(c0.x << 3) + l8];
        float w0 = __int_as_float(c0.y);
        #pragma unroll
        for (int k = 0; k < 8; k++)
            acc[k] += w0 * (float)v0[k];
    }

    #pragma unroll
    for (int k = 0; k < 8; k++) {
        acc[k] += __shfl_xor(acc[k], 8, 64);
        acc[k] += __shfl_xor(acc[k], 16, 64);
        acc[k] += __shfl_xor(acc[k], 32, 64);
    }

    if (sub == 0) {
        h8 o;
        #pragma unroll
        for (int k = 0; k < 8; k++) o[k] = (_Float16)acc[k];
        Xout[(wid << 3) + l8] = o;
    }
}

// out = 0.25*(x0 + x1 + x2 + x3), 8 elems/thread
__global__ void final_kernel(const float* __restrict__ ue, const float* __restrict__ ie,
                             const h8* __restrict__ X1, const h8* __restrict__ X2,
                             const h8* __restrict__ X3, float* __restrict__ out,
                             int nu_elems, int total8) {
    int t = blockIdx.x * blockDim.x + threadIdx.x;
    if (t >= total8) return;
    int base = t << 3;
    const f4* src = (const f4*)((base < nu_elems) ? (ue + base) : (ie + (base - nu_elems)));
    f4 a = src[0], b = src[1];
    h8 v1 = X1[t], v2 = X2[t], v3 = X3[t];
    f4 o0, o1;
    o0.x = 0.25f * (a.x + (float)v1[0] + (float)v2[0] + (float)v3[0]);
    o0.y = 0.25f * (a.y + (float)v1[1] + (float)v2[1] + (float)v3[1]);
    o0.z = 0.25f * (a.z + (float)v1[2] + (float)v2[2] + (float)v3[2]);
    o0.w = 0.25f * (a.w + (float)v1[3] + (float)v2[3] + (float)v3[3]);
    o1.x = 0.25f * (b.x + (float)v1[4] + (float)v2[4] + (float)v3[4]);
    o1.y = 0.25f * (b.y + (float)v1[5] + (float)v2[5] + (float)v3[5]);
    o1.z = 0.25f * (b.z + (float)v1[6] + (float)v2[6] + (float)v3[6]);
    o1.w = 0.25f * (b.w + (float)v1[7] + (float)v2[7] + (float)v3[7]);
    f4* dst = (f4*)(out + base);
    dst[0] = o0;
    dst[1] = o1;
}

extern "C" void kernel_launch(void* const* d_in, const int* in_sizes, int n_in,
                              void* d_out, int out_size, void* d_ws, size_t ws_size,
                              hipStream_t stream) {
    const int* edge_row = (const int*)d_in[0];
    const int* edge_col = (const int*)d_in[1];
    const float* edge_w = (const float*)d_in[2];
    const float* user_emb = (const float*)d_in[3];
    const float* item_emb = (const float*)d_in[4];

    const int E = in_sizes[0];
    const int nu_elems = in_sizes[3];
    const int ni_elems = in_sizes[4];
    const int total = nu_elems + ni_elems;
    const int N = total / EMB;                      // 150000
    const int NBUCK = (N + (1 << BUCKET_SHIFT) - 1) >> BUCKET_SHIFT;  // 293

    size_t off = 0;
    auto carve = [&](size_t bytes) {
        void* p = (char*)d_ws + off;
        off += (bytes + 255) & ~(size_t)255;
        return p;
    };
    h8*   X0h     = (h8*)carve((size_t)total * 2);
    h8*   X1h     = (h8*)carve((size_t)total * 2);
    h8*   X2h     = (h8*)carve((size_t)total * 2);
    int*  counts  = (int*)carve((size_t)(N + 1) * 4);
    int*  row_ptr = (int*)carve((size_t)(N + 1) * 4);
    int*  cursor1 = (int*)carve((size_t)NBUCK * 4);
    int*  tmp_r   = (int*)carve((size_t)E * 4);
    int2* tmp_cw  = (int2*)carve((size_t)E * 8);
    int2* cw      = (int2*)carve((size_t)E * 8);
    int*  bsums   = (int*)carve(4096);
    (void)ws_size;

    float* out = (float*)d_out;

    const int B = 256;
    const int nScan = N + 1;
    const int nb = (nScan + 1023) / 1024;
    const int total8 = total / 8;

    hipMemsetAsync(counts, 0, (size_t)(N + 1) * 4, stream);

    hist_kernel<<<(E + B - 1) / B, B, 0, stream>>>(edge_row, counts, E);
    scan_blocks<<<nb, B, 0, stream>>>(counts, row_ptr, bsums, nScan);
    scan_sums<<<1, 64, 0, stream>>>(bsums, nb);
    scan_add<<<(nScan + B - 1) / B, B, 0, stream>>>(row_ptr, bsums, nScan);
    init_cursor1<<<(NBUCK + B - 1) / B, B, 0, stream>>>(row_ptr, cursor1, NBUCK, N);
    convert_kernel<<<(total8 + B - 1) / B, B, 0, stream>>>(user_emb, item_emb, X0h,
                                                           nu_elems, total8);
    scatter1<<<(E + S1_CHUNK - 1) / S1_CHUNK, B, 0, stream>>>(edge_row, edge_col, edge_w,
                                                              cursor1, tmp_r, tmp_cw,
                                                              NBUCK, E);
    scatter2<<<NBUCK, B, 0, stream>>>(row_ptr, tmp_r, tmp_cw, cw, N);

    const int spmmBlocks = (N * 64 + B - 1) / B;
    spmm_kernel<<<spmmBlocks, B, 0, stream>>>(row_ptr, cw, X0h, X1h, N);
    spmm_kernel<<<spmmBlocks, B, 0, stream>>>(row_ptr, cw, X1h, X2h, N);
    spmm_kernel<<<spmmBlocks, B, 0, stream>>>(row_ptr, cw, X2h, X0h, N);  // X3 -> reuse X0h

    final_kernel<<<(total8 + B - 1) / B, B, 0, stream>>>(user_emb, item_emb,
                                                         X1h, X2h, X0h, out,
                                                         nu_elems, total8);
}

// Round 4
// 334.490 us; speedup vs baseline: 1.9062x; 1.1794x over previous
//
#include <hip/hip_runtime.h>
#include <hip/hip_bf16.h>

// LightGCN propagation: x = concat(user,item) [150000,64] f32;
// acc = x; 3x { x = A@x (COO spmm, E=1.2M); acc += x }; out = acc/4.
//
// Pipeline (9 dispatches):
//  1) memset bucket counts (293 x 4B)
//  2) bucket_hist: LDS-aggregated bucket histogram (bucket = row>>9),
//     86K global atomics instead of 1.2M row atomics.
//  3) scan_buckets: single-wave shfl scan of 293 counts -> bucket bases
//     (replaces the 150K global scan + the SERIAL 147-step scan_sums).
//  4) convert: x0 fp32 -> fp16 staging.
//  5) scatter1: LDS-rank edges per bucket in 4096-edge blocks, reserve
//     chunks via bucket cursors, write (r,c,w) bucket-contiguous.
//  6) scatter2: one block per bucket; LDS row-histogram (512 counters) +
//     LDS pair-scan -> writes row_ptr AND places edges. No global atomics.
//  7-9) spmm x3: 1 wave/row, 8 edge-groups x 8 lanes x 16B fp16 loads
//     (16 gathers in flight). Layer 3 fuses out = 0.25*(x0+x1+x2+x3),
//     skipping the X3 store and the separate final pass.

#define EMB 64
#define BUCKET_SHIFT 9
#define BROWS (1 << BUCKET_SHIFT)
#define S1_CHUNK 4096
#define NBUCK_PAD 320

typedef _Float16 h8 __attribute__((ext_vector_type(8)));
typedef float f4 __attribute__((ext_vector_type(4)));

// ---- bucket histogram (LDS-aggregated) ----
__global__ void bucket_hist(const int* __restrict__ row, int* __restrict__ bcount,
                            int nbuck, int E) {
    __shared__ int l[NBUCK_PAD];
    int t = threadIdx.x;
    for (int j = t; j < nbuck; j += 256) l[j] = 0;
    __syncthreads();
    int c0 = blockIdx.x * S1_CHUNK;
    #pragma unroll
    for (int i = 0; i < 16; i++) {
        int e = c0 + i * 256 + t;
        if (e < E) atomicAdd(&l[row[e] >> BUCKET_SHIFT], 1);
    }
    __syncthreads();
    for (int j = t; j < nbuck; j += 256) {
        int c = l[j];
        if (c) atomicAdd(&bcount[j], c);
    }
}

// ---- single-wave scan of bucket counts -> exclusive bases ----
__global__ void scan_buckets(const int* __restrict__ bc, int* __restrict__ bscan,
                             int* __restrict__ cursor1, int nbuck) {
    int lane = threadIdx.x;  // 64 threads
    int carry = 0;
    for (int base = 0; base <= nbuck; base += 64) {
        int j = base + lane;
        int v = (j < nbuck) ? bc[j] : 0;
        int s = v;
        #pragma unroll
        for (int off = 1; off < 64; off <<= 1) {
            int tt = __shfl_up(s, off, 64);
            if (lane >= off) s += tt;
        }
        int excl = carry + s - v;
        if (j < nbuck) cursor1[j] = excl;
        if (j <= nbuck) bscan[j] = excl;
        carry += __shfl(s, 63, 64);
    }
}

// ---- x0 fp32 (split arrays) -> fp16 ----
__global__ void convert_kernel(const float* __restrict__ ue, const float* __restrict__ ie,
                               h8* __restrict__ X0h, int nu_elems, int total8) {
    int t = blockIdx.x * blockDim.x + threadIdx.x;
    if (t >= total8) return;
    int base = t << 3;
    const f4* src = (const f4*)((base < nu_elems) ? (ue + base) : (ie + (base - nu_elems)));
    f4 a = src[0], b = src[1];
    h8 o;
    o[0] = (_Float16)a.x; o[1] = (_Float16)a.y; o[2] = (_Float16)a.z; o[3] = (_Float16)a.w;
    o[4] = (_Float16)b.x; o[5] = (_Float16)b.y; o[6] = (_Float16)b.z; o[7] = (_Float16)b.w;
    X0h[t] = o;
}

// ---- binned sort phase 1 ----
__global__ void scatter1(const int* __restrict__ row, const int* __restrict__ col,
                         const float* __restrict__ w, int* __restrict__ cursor1,
                         int* __restrict__ tmp_r, int2* __restrict__ tmp_cw,
                         int nbuck, int E) {
    __shared__ int lcount[NBUCK_PAD];
    __shared__ int lbase[NBUCK_PAD];
    int t = threadIdx.x;
    int c0 = blockIdx.x * S1_CHUNK;
    for (int j = t; j < nbuck; j += 256) lcount[j] = 0;
    __syncthreads();
    int pk[16];
    #pragma unroll
    for (int i = 0; i < 16; i++) {
        int e = c0 + i * 256 + t;
        int p = -1;
        if (e < E) {
            int b = row[e] >> BUCKET_SHIFT;
            int r = atomicAdd(&lcount[b], 1);
            p = (b << 13) | r;
        }
        pk[i] = p;
    }
    __syncthreads();
    for (int j = t; j < nbuck; j += 256) {
        int c = lcount[j];
        if (c) lbase[j] = atomicAdd(&cursor1[j], c);
    }
    __syncthreads();
    #pragma unroll
    for (int i = 0; i < 16; i++) {
        int e = c0 + i * 256 + t;
        if (e < E) {
            int b = pk[i] >> 13;
            int r = pk[i] & 8191;
            int p = lbase[b] + r;
            tmp_r[p] = row[e];
            tmp_cw[p] = make_int2(col[e], __float_as_int(w[e]));
        }
    }
}

// ---- binned sort phase 2: row-hist + scan in LDS; writes row_ptr + cw ----
__global__ void scatter2(const int* __restrict__ bscan, const int* __restrict__ tmp_r,
                         const int2* __restrict__ tmp_cw, int2* __restrict__ cw,
                         int* __restrict__ rp, int nrows) {
    __shared__ int cnt[BROWS];
    __shared__ int waveSums[4];
    int t = threadIdx.x;
    int j = blockIdx.x;
    int rowbase = j << BUCKET_SHIFT;
    int rows_here = nrows - rowbase;
    if (rows_here > BROWS) rows_here = BROWS;
    int bbase = bscan[j];
    int end = bscan[j + 1];

    for (int k = t; k < BROWS; k += 256) cnt[k] = 0;
    __syncthreads();
    for (int p = bbase + t; p < end; p += 256)
        atomicAdd(&cnt[tmp_r[p] & (BROWS - 1)], 1);
    __syncthreads();

    // pair scan: thread t owns elems 2t, 2t+1
    int k0 = t << 1, k1 = k0 + 1;
    int c0 = cnt[k0], c1 = cnt[k1];
    int psum = c0 + c1;
    int lane = t & 63;
    int wave = t >> 6;
    int s = psum;
    #pragma unroll
    for (int off = 1; off < 64; off <<= 1) {
        int tt = __shfl_up(s, off, 64);
        if (lane >= off) s += tt;
    }
    if (lane == 63) waveSums[wave] = s;
    __syncthreads();
    int woff = 0;
    for (int w = 0; w < wave; w++) woff += waveSums[w];
    int e0 = woff + s - psum;   // exclusive prefix of elem k0
    int e1 = e0 + c0;
    if (k0 < rows_here) rp[rowbase + k0] = bbase + e0;
    if (k1 < rows_here) rp[rowbase + k1] = bbase + e1;
    cnt[k0] = e0;
    cnt[k1] = e1;
    __syncthreads();

    for (int p = bbase + t; p < end; p += 256) {
        int2 v = tmp_cw[p];
        int r = tmp_r[p] & (BROWS - 1);
        int pos = bbase + atomicAdd(&cnt[r], 1);
        cw[pos] = v;
    }
    if (j == gridDim.x - 1 && t == 0) rp[nrows] = end;
}

// ---- spmm: 1 wave/row; 8 edge-groups x 8 lanes; 16B fp16 loads; 2x unroll
// LAST fuses: out = 0.25*(x0 + x1 + x2 + acc)
template <bool LAST>
__global__ void spmm_kernel(const int* __restrict__ rp, const int2* __restrict__ cw,
                            const h8* __restrict__ Xin, h8* __restrict__ Xout,
                            const h8* __restrict__ X1,
                            const float* __restrict__ ue, const float* __restrict__ ie,
                            int nu_elems, int nuRows,
                            float* __restrict__ out, int nrows) {
    int wid = (blockIdx.x * blockDim.x + threadIdx.x) >> 6;
    if (wid >= nrows) return;
    int lane = threadIdx.x & 63;
    int sub = lane >> 3;
    int l8 = lane & 7;

    int beg = rp[wid];
    int end = rp[wid + 1];

    float acc[8];
    #pragma unroll
    for (int k = 0; k < 8; k++) acc[k] = 0.f;

    int e = beg + sub;
    for (; e + 8 < end; e += 16) {
        int2 c0 = cw[e];
        int2 c1 = cw[e + 8];
        h8 v0 = Xin[(c0.x << 3) + l8];
        h8 v1 = Xin[(c1.x << 3) + l8];
        float w0 = __int_as_float(c0.y);
        float w1 = __int_as_float(c1.y);
        #pragma unroll
        for (int k = 0; k < 8; k++)
            acc[k] += w0 * (float)v0[k] + w1 * (float)v1[k];
    }
    if (e < end) {
        int2 c0 = cw[e];
        h8 v0 = Xin[(c0.x << 3) + l8];
        float w0 = __int_as_float(c0.y);
        #pragma unroll
        for (int k = 0; k < 8; k++)
            acc[k] += w0 * (float)v0[k];
    }

    #pragma unroll
    for (int k = 0; k < 8; k++) {
        acc[k] += __shfl_xor(acc[k], 8, 64);
        acc[k] += __shfl_xor(acc[k], 16, 64);
        acc[k] += __shfl_xor(acc[k], 32, 64);
    }

    if (sub == 0) {
        if (LAST) {
            int base = (wid << 6) + (l8 << 3);
            const f4* x0p = (const f4*)((wid < nuRows) ? (ue + base)
                                                       : (ie + (base - nu_elems)));
            f4 a = x0p[0], b = x0p[1];
            h8 v1 = X1[(wid << 3) + l8];
            h8 v2 = Xin[(wid << 3) + l8];
            f4 o0, o1;
            o0.x = 0.25f * (a.x + (float)v1[0] + (float)v2[0] + acc[0]);
            o0.y = 0.25f * (a.y + (float)v1[1] + (float)v2[1] + acc[1]);
            o0.z = 0.25f * (a.z + (float)v1[2] + (float)v2[2] + acc[2]);
            o0.w = 0.25f * (a.w + (float)v1[3] + (float)v2[3] + acc[3]);
            o1.x = 0.25f * (b.x + (float)v1[4] + (float)v2[4] + acc[4]);
            o1.y = 0.25f * (b.y + (float)v1[5] + (float)v2[5] + acc[5]);
            o1.z = 0.25f * (b.z + (float)v1[6] + (float)v2[6] + acc[6]);
            o1.w = 0.25f * (b.w + (float)v1[7] + (float)v2[7] + acc[7]);
            f4* dst = (f4*)(out + base);
            dst[0] = o0;
            dst[1] = o1;
        } else {
            h8 o;
            #pragma unroll
            for (int k = 0; k < 8; k++) o[k] = (_Float16)acc[k];
            Xout[(wid << 3) + l8] = o;
        }
    }
}

extern "C" void kernel_launch(void* const* d_in, const int* in_sizes, int n_in,
                              void* d_out, int out_size, void* d_ws, size_t ws_size,
                              hipStream_t stream) {
    const int* edge_row = (const int*)d_in[0];
    const int* edge_col = (const int*)d_in[1];
    const float* edge_w = (const float*)d_in[2];
    const float* user_emb = (const float*)d_in[3];
    const float* item_emb = (const float*)d_in[4];

    const int E = in_sizes[0];
    const int nu_elems = in_sizes[3];
    const int ni_elems = in_sizes[4];
    const int total = nu_elems + ni_elems;
    const int N = total / EMB;                      // 150000
    const int nuRows = nu_elems / EMB;              // 100000
    const int NBUCK = (N + BROWS - 1) >> BUCKET_SHIFT;  // 293

    size_t off = 0;
    auto carve = [&](size_t bytes) {
        void* p = (char*)d_ws + off;
        off += (bytes + 255) & ~(size_t)255;
        return p;
    };
    h8*   X0h     = (h8*)carve((size_t)total * 2);
    h8*   X1h     = (h8*)carve((size_t)total * 2);
    h8*   X2h     = (h8*)carve((size_t)total * 2);
    int*  row_ptr = (int*)carve((size_t)(N + 1) * 4);
    int*  bcount  = (int*)carve((size_t)NBUCK * 4);
    int*  bscan   = (int*)carve((size_t)(NBUCK + 1) * 4);
    int*  cursor1 = (int*)carve((size_t)NBUCK * 4);
    int*  tmp_r   = (int*)carve((size_t)E * 4);
    int2* tmp_cw  = (int2*)carve((size_t)E * 8);
    int2* cw      = (int2*)carve((size_t)E * 8);
    (void)ws_size;

    float* out = (float*)d_out;

    const int B = 256;
    const int total8 = total / 8;
    const int edgeBlocks = (E + S1_CHUNK - 1) / S1_CHUNK;

    hipMemsetAsync(bcount, 0, (size_t)NBUCK * 4, stream);
    bucket_hist<<<edgeBlocks, B, 0, stream>>>(edge_row, bcount, NBUCK, E);
    scan_buckets<<<1, 64, 0, stream>>>(bcount, bscan, cursor1, NBUCK);
    convert_kernel<<<(total8 + B - 1) / B, B, 0, stream>>>(user_emb, item_emb, X0h,
                                                           nu_elems, total8);
    scatter1<<<edgeBlocks, B, 0, stream>>>(edge_row, edge_col, edge_w,
                                           cursor1, tmp_r, tmp_cw, NBUCK, E);
    scatter2<<<NBUCK, B, 0, stream>>>(bscan, tmp_r, tmp_cw, cw, row_ptr, N);

    const int spmmBlocks = (N * 64 + B - 1) / B;
    spmm_kernel<false><<<spmmBlocks, B, 0, stream>>>(row_ptr, cw, X0h, X1h,
                                                     nullptr, nullptr, nullptr,
                                                     0, 0, nullptr, N);
    spmm_kernel<false><<<spmmBlocks, B, 0, stream>>>(row_ptr, cw, X1h, X2h,
                                                     nullptr, nullptr, nullptr,
                                                     0, 0, nullptr, N);
    spmm_kernel<true><<<spmmBlocks, B, 0, stream>>>(row_ptr, cw, X2h, nullptr,
                                                    X1h, user_emb, item_emb,
                                                    nu_elems, nuRows, out, N);
}

// Round 5
// 301.555 us; speedup vs baseline: 2.1143x; 1.1092x over previous
//
#include <hip/hip_runtime.h>
#include <hip/hip_bf16.h>

// LightGCN propagation: x = concat(user,item) [150000,64] f32;
// acc = x; 3x { x = A@x (COO spmm, E=1.2M); acc += x }; out = acc/4.
//
// Pipeline (8 dispatches):
//  1) memset bucket counts (293 x 4B)
//  2) hist_convert (role-split grid): LDS-aggregated bucket histogram
//     (bucket = row>>9) + x0 fp32->fp16 staging.
//  3) scan_buckets: single-wave shfl scan of 293 counts -> bucket bases.
//  4) scatter1: 512thr/2048 edges per block; LDS-rank per bucket; write
//     PACKED tmp: pk=(col<<9)|(row&511) [4B] + w [4B]  (8B/edge).
//  5) scatter2: one 512-thr block per bucket; rank-atomics return final
//     ranks (register-cached), LDS scan of 512 row counters -> row_ptr +
//     placement; only tmp_w re-read in place phase.
//  6-8) spmm x3: 1 wave/row, 8 edge-groups x 8 lanes x 16B fp16 loads
//     (16 gathers in flight), packed-f32 accumulate. Layer 3 fuses
//     out = 0.25*(x0h+x1+x2+acc), no X3 store, x0 read as fp16.

#define EMB 64
#define BUCKET_SHIFT 9
#define BROWS (1 << BUCKET_SHIFT)
#define NBUCK_PAD 320
#define HIST_CHUNK 4096
#define S1_CHUNK 2048
#define S2_CAP 16

typedef _Float16 h8 __attribute__((ext_vector_type(8)));
typedef _Float16 h2v __attribute__((ext_vector_type(2)));
typedef float f2v __attribute__((ext_vector_type(2)));
typedef float f4 __attribute__((ext_vector_type(4)));

union H8U { h8 v; h2v p[4]; };

// ---- fused bucket histogram + fp32->fp16 convert (role-split) ----
__global__ void hist_convert(const int* __restrict__ row, int* __restrict__ bcount,
                             const float* __restrict__ ue, const float* __restrict__ ie,
                             h8* __restrict__ X0h, int nu_elems, int total8,
                             int nbuck, int E, int histBlocks) {
    int t = threadIdx.x;
    if ((int)blockIdx.x < histBlocks) {
        __shared__ int l[NBUCK_PAD];
        for (int j = t; j < nbuck; j += 512) l[j] = 0;
        __syncthreads();
        int c0 = blockIdx.x * HIST_CHUNK;
        #pragma unroll
        for (int i = 0; i < HIST_CHUNK / 512; i++) {
            int e = c0 + i * 512 + t;
            if (e < E) atomicAdd(&l[row[e] >> BUCKET_SHIFT], 1);
        }
        __syncthreads();
        for (int j = t; j < nbuck; j += 512) {
            int c = l[j];
            if (c) atomicAdd(&bcount[j], c);
        }
    } else {
        int g = (blockIdx.x - histBlocks) * 512 + t;
        if (g >= total8) return;
        int base = g << 3;
        const f4* src = (const f4*)((base < nu_elems) ? (ue + base)
                                                      : (ie + (base - nu_elems)));
        f4 a = src[0], b = src[1];
        h8 o;
        o[0] = (_Float16)a.x; o[1] = (_Float16)a.y; o[2] = (_Float16)a.z; o[3] = (_Float16)a.w;
        o[4] = (_Float16)b.x; o[5] = (_Float16)b.y; o[6] = (_Float16)b.z; o[7] = (_Float16)b.w;
        X0h[g] = o;
    }
}

// ---- single-wave scan of bucket counts ----
__global__ void scan_buckets(const int* __restrict__ bc, int* __restrict__ bscan,
                             int* __restrict__ cursor1, int nbuck) {
    int lane = threadIdx.x;  // 64 threads
    int carry = 0;
    for (int base = 0; base <= nbuck; base += 64) {
        int j = base + lane;
        int v = (j < nbuck) ? bc[j] : 0;
        int s = v;
        #pragma unroll
        for (int off = 1; off < 64; off <<= 1) {
            int tt = __shfl_up(s, off, 64);
            if (lane >= off) s += tt;
        }
        int excl = carry + s - v;
        if (j < nbuck) cursor1[j] = excl;
        if (j <= nbuck) bscan[j] = excl;
        carry += __shfl(s, 63, 64);
    }
}

// ---- binned sort phase 1: packed 8B records ----
__global__ void scatter1(const int* __restrict__ row, const int* __restrict__ col,
                         const float* __restrict__ w, int* __restrict__ cursor1,
                         int* __restrict__ tmp_pk, float* __restrict__ tmp_w,
                         int nbuck, int E) {
    __shared__ int lcount[NBUCK_PAD];
    __shared__ int lbase[NBUCK_PAD];
    int t = threadIdx.x;
    int c0 = blockIdx.x * S1_CHUNK;
    for (int j = t; j < nbuck; j += 512) lcount[j] = 0;
    __syncthreads();
    int pkc[S1_CHUNK / 512];   // (b<<12)|rank
    int cc[S1_CHUNK / 512];
    int rr[S1_CHUNK / 512];
    float ww[S1_CHUNK / 512];
    #pragma unroll
    for (int i = 0; i < S1_CHUNK / 512; i++) {
        int e = c0 + i * 512 + t;
        pkc[i] = -1;
        if (e < E) {
            int r = row[e];
            int b = r >> BUCKET_SHIFT;
            int rank = atomicAdd(&lcount[b], 1);
            pkc[i] = (b << 12) | rank;
            cc[i] = col[e];
            rr[i] = r & (BROWS - 1);
            ww[i] = w[e];
        }
    }
    __syncthreads();
    for (int j = t; j < nbuck; j += 512) {
        int c = lcount[j];
        if (c) lbase[j] = atomicAdd(&cursor1[j], c);
    }
    __syncthreads();
    #pragma unroll
    for (int i = 0; i < S1_CHUNK / 512; i++) {
        if (pkc[i] >= 0) {
            int b = pkc[i] >> 12;
            int p = lbase[b] + (pkc[i] & 4095);
            tmp_pk[p] = (cc[i] << BUCKET_SHIFT) | rr[i];
            tmp_w[p] = ww[i];
        }
    }
}

// ---- binned sort phase 2: rank + scan + place; writes row_ptr and cw ----
__global__ void scatter2(const int* __restrict__ bscan, const int* __restrict__ tmp_pk,
                         const float* __restrict__ tmp_w, int2* __restrict__ cw,
                         int* __restrict__ rp, int nrows, int nbuck) {
    __shared__ int cnt[BROWS];
    __shared__ int wS[8];
    int t = threadIdx.x;
    int j = blockIdx.x;
    int rowbase = j << BUCKET_SHIFT;
    int rows_here = nrows - rowbase;
    if (rows_here > BROWS) rows_here = BROWS;
    int bbase = bscan[j];
    int end = bscan[j + 1];
    int num = end - bbase;
    int iters = (num + 511) >> 9;

    cnt[t] = 0;
    __syncthreads();

    int pkc[S2_CAP];
    int rk[S2_CAP];
    bool cached = (iters <= S2_CAP);
    if (cached) {
        for (int i = 0; i < iters; i++) {
            int p = bbase + i * 512 + t;
            pkc[i] = -1;
            if (p < end) {
                int pk = tmp_pk[p];
                pkc[i] = pk;
                rk[i] = atomicAdd(&cnt[pk & (BROWS - 1)], 1);
            }
        }
    } else {
        for (int p = bbase + t; p < end; p += 512)
            atomicAdd(&cnt[tmp_pk[p] & (BROWS - 1)], 1);
    }
    __syncthreads();

    // scan of 512 counters, one per thread
    int v = cnt[t];
    int lane = t & 63;
    int wave = t >> 6;
    int s = v;
    #pragma unroll
    for (int off = 1; off < 64; off <<= 1) {
        int tt = __shfl_up(s, off, 64);
        if (lane >= off) s += tt;
    }
    if (lane == 63) wS[wave] = s;
    __syncthreads();
    int woff = 0;
    for (int w = 0; w < wave; w++) woff += wS[w];
    int excl = woff + s - v;
    if (t < rows_here) rp[rowbase + t] = bbase + excl;
    __syncthreads();
    cnt[t] = excl;
    __syncthreads();

    if (cached) {
        for (int i = 0; i < iters; i++) {
            if (pkc[i] >= 0) {
                int p = bbase + i * 512 + t;
                int r = pkc[i] & (BROWS - 1);
                int c = pkc[i] >> BUCKET_SHIFT;
                cw[bbase + cnt[r] + rk[i]] = make_int2(c, __float_as_int(tmp_w[p]));
            }
        }
    } else {
        for (int p = bbase + t; p < end; p += 512) {
            int pk = tmp_pk[p];
            int r = pk & (BROWS - 1);
            int pos = bbase + atomicAdd(&cnt[r], 1);
            cw[pos] = make_int2(pk >> BUCKET_SHIFT, __float_as_int(tmp_w[p]));
        }
    }
    if (j == nbuck - 1 && t == 0) rp[nrows] = end;
}

// ---- spmm: 1 wave/row; 8 edge-groups x 8 lanes; 16B fp16 loads ----
// LAST fuses out = 0.25*(x0h + x1 + x2 + acc)
template <bool LAST>
__global__ __launch_bounds__(256) void spmm_kernel(
        const int* __restrict__ rp, const int2* __restrict__ cw,
        const h8* __restrict__ Xin, h8* __restrict__ Xout,
        const h8* __restrict__ X0, const h8* __restrict__ X1,
        float* __restrict__ out, int nrows) {
    int wid = (blockIdx.x * blockDim.x + threadIdx.x) >> 6;
    if (wid >= nrows) return;
    int lane = threadIdx.x & 63;
    int sub = lane >> 3;
    int l8 = lane & 7;

    int beg = rp[wid];
    int end = rp[wid + 1];

    f2v acc2[4];
    #pragma unroll
    for (int k = 0; k < 4; k++) acc2[k] = (f2v){0.f, 0.f};

    int e = beg + sub;
    for (; e + 8 < end; e += 16) {
        int2 c0 = cw[e];
        int2 c1 = cw[e + 8];
        H8U v0, v1;
        v0.v = Xin[(c0.x << 3) + l8];
        v1.v = Xin[(c1.x << 3) + l8];
        float w0 = __int_as_float(c0.y);
        float w1 = __int_as_float(c1.y);
        f2v w0p = (f2v){w0, w0};
        f2v w1p = (f2v){w1, w1};
        #pragma unroll
        for (int k = 0; k < 4; k++) {
            acc2[k] += w0p * __builtin_convertvector(v0.p[k], f2v);
            acc2[k] += w1p * __builtin_convertvector(v1.p[k], f2v);
        }
    }
    if (e < end) {
        int2 c0 = cw[e];
        H8U v0;
        v0.v = Xin[(c0.x << 3) + l8];
        float w0 = __int_as_float(c0.y);
        f2v w0p = (f2v){w0, w0};
        #pragma unroll
        for (int k = 0; k < 4; k++)
            acc2[k] += w0p * __builtin_convertvector(v0.p[k], f2v);
    }

    float* a = (float*)acc2;
    #pragma unroll
    for (int k = 0; k < 8; k++) {
        a[k] += __shfl_xor(a[k], 8, 64);
        a[k] += __shfl_xor(a[k], 16, 64);
        a[k] += __shfl_xor(a[k], 32, 64);
    }

    if (sub == 0) {
        if (LAST) {
            h8 x0 = X0[(wid << 3) + l8];
            h8 v1 = X1[(wid << 3) + l8];
            h8 v2 = Xin[(wid << 3) + l8];
            int base = (wid << 6) + (l8 << 3);
            f4 o0, o1;
            o0.x = 0.25f * ((float)x0[0] + (float)v1[0] + (float)v2[0] + a[0]);
            o0.y = 0.25f * ((float)x0[1] + (float)v1[1] + (float)v2[1] + a[1]);
            o0.z = 0.25f * ((float)x0[2] + (float)v1[2] + (float)v2[2] + a[2]);
            o0.w = 0.25f * ((float)x0[3] + (float)v1[3] + (float)v2[3] + a[3]);
            o1.x = 0.25f * ((float)x0[4] + (float)v1[4] + (float)v2[4] + a[4]);
            o1.y = 0.25f * ((float)x0[5] + (float)v1[5] + (float)v2[5] + a[5]);
            o1.z = 0.25f * ((float)x0[6] + (float)v1[6] + (float)v2[6] + a[6]);
            o1.w = 0.25f * ((float)x0[7] + (float)v1[7] + (float)v2[7] + a[7]);
            f4* dst = (f4*)(out + base);
            dst[0] = o0;
            dst[1] = o1;
        } else {
            h8 o;
            #pragma unroll
            for (int k = 0; k < 8; k++) o[k] = (_Float16)a[k];
            Xout[(wid << 3) + l8] = o;
        }
    }
}

extern "C" void kernel_launch(void* const* d_in, const int* in_sizes, int n_in,
                              void* d_out, int out_size, void* d_ws, size_t ws_size,
                              hipStream_t stream) {
    const int* edge_row = (const int*)d_in[0];
    const int* edge_col = (const int*)d_in[1];
    const float* edge_w = (const float*)d_in[2];
    const float* user_emb = (const float*)d_in[3];
    const float* item_emb = (const float*)d_in[4];

    const int E = in_sizes[0];
    const int nu_elems = in_sizes[3];
    const int ni_elems = in_sizes[4];
    const int total = nu_elems + ni_elems;
    const int N = total / EMB;                           // 150000
    const int NBUCK = (N + BROWS - 1) >> BUCKET_SHIFT;   // 293

    size_t off = 0;
    auto carve = [&](size_t bytes) {
        void* p = (char*)d_ws + off;
        off += (bytes + 255) & ~(size_t)255;
        return p;
    };
    h8*    X0h     = (h8*)carve((size_t)total * 2);
    h8*    X1h     = (h8*)carve((size_t)total * 2);
    h8*    X2h     = (h8*)carve((size_t)total * 2);
    int*   row_ptr = (int*)carve((size_t)(N + 1) * 4);
    int*   bcount  = (int*)carve((size_t)NBUCK * 4);
    int*   bscan   = (int*)carve((size_t)(NBUCK + 1) * 4);
    int*   cursor1 = (int*)carve((size_t)NBUCK * 4);
    int*   tmp_pk  = (int*)carve((size_t)E * 4);
    float* tmp_w   = (float*)carve((size_t)E * 4);
    int2*  cw      = (int2*)carve((size_t)E * 8);
    (void)ws_size;

    float* out = (float*)d_out;

    const int total8 = total / 8;
    const int histBlocks = (E + HIST_CHUNK - 1) / HIST_CHUNK;
    const int convBlocks = (total8 + 511) / 512;

    hipMemsetAsync(bcount, 0, (size_t)NBUCK * 4, stream);
    hist_convert<<<histBlocks + convBlocks, 512, 0, stream>>>(
        edge_row, bcount, user_emb, item_emb, X0h, nu_elems, total8,
        NBUCK, E, histBlocks);
    scan_buckets<<<1, 64, 0, stream>>>(bcount, bscan, cursor1, NBUCK);
    scatter1<<<(E + S1_CHUNK - 1) / S1_CHUNK, 512, 0, stream>>>(
        edge_row, edge_col, edge_w, cursor1, tmp_pk, tmp_w, NBUCK, E);
    scatter2<<<NBUCK, 512, 0, stream>>>(bscan, tmp_pk, tmp_w, cw, row_ptr, N, NBUCK);

    const int spmmBlocks = (N * 64 + 255) / 256;
    spmm_kernel<false><<<spmmBlocks, 256, 0, stream>>>(row_ptr, cw, X0h, X1h,
                                                       nullptr, nullptr, nullptr, N);
    spmm_kernel<false><<<spmmBlocks, 256, 0, stream>>>(row_ptr, cw, X1h, X2h,
                                                       nullptr, nullptr, nullptr, N);
    spmm_kernel<true><<<spmmBlocks, 256, 0, stream>>>(row_ptr, cw, X2h, nullptr,
                                                      X0h, X1h, out, N);
}